// Round 1
// 5828.238 us; speedup vs baseline: 1.8253x; 1.8253x over previous
//
#include <hip/hip_runtime.h>
#include <hip/hip_bf16.h>
#include <stdint.h>

// BioDecoder (all inputs/outputs FP32; bf16 used internally for MFMA):
//   prep: f32->bf16 convert of w_hh_l0, w_hh_l1, out_w into ws
//   k_embed_xp0 -> xp (f32)
//   k_scan L0 (MFMA, 1 WG, w_hh RESIDENT in VGPR+LDS) -> hs1 (bf16)
//   k_xp1 -> xp (f32)
//   k_scan L1 -> hs2 (bf16)
//   k_gate -> gate (f32)
//   k_out (MFMA bf16, f32 epilogue) -> d_out (f32)
//
// ws layout (bytes):
//   xp    @ 0          : 4088*1024 f32  = 16,744,448
//   hs1   @ 16,744,448 : 4096*256 bf16  =  2,097,152
//   hs2   @ 18,841,600 : 4096*256 bf16  =  2,097,152
//   gate  @ 20,938,752 : 4088 f32       (pad to 16,352 -> next @ 20,955,104)
//   whh0b @ 20,955,104 : 1024*256 bf16  =    524,288
//   whh1b @ 21,479,392 : 1024*256 bf16  =    524,288
//   owb   @ 22,003,680 : 32000*256 bf16 = 16,384,000
//   total 38,387,680 bytes (~38.4 MB)

typedef short bf16x8 __attribute__((ext_vector_type(8)));
typedef float f32x4 __attribute__((ext_vector_type(4)));

__device__ __forceinline__ float b2f(unsigned short u) {
    union { unsigned int i; float f; } v; v.i = ((unsigned int)u) << 16; return v.f;
}
__device__ __forceinline__ unsigned short f2b(float f) {
    union { float f; unsigned int i; } v; v.f = f;
    unsigned int x = v.i;
    return (unsigned short)((x + 0x7fffu + ((x >> 16) & 1u)) >> 16);  // RNE
}
__device__ __forceinline__ float sigmoidf_(float x) { return 1.0f / (1.0f + __expf(-x)); }
__device__ __forceinline__ float tanhf_(float x) {
    float xc = fminf(fmaxf(x, -15.f), 15.f);
    float e = __expf(2.f * xc);
    return (e - 1.f) / (e + 1.f);
}

// ---------------- prep: f32 -> bf16 --------------------------------------------
__global__ void k_cvt(const float* __restrict__ src, unsigned short* __restrict__ dst, int n)
{
    int i = (blockIdx.x * 256 + threadIdx.x) * 4;
    if (i < n) {
        float4 v = *(const float4*)(src + i);
        unsigned short o[4] = { f2b(v.x), f2b(v.y), f2b(v.z), f2b(v.w) };
        *(uint2*)(dst + i) = *(const uint2*)o;
    }
}

// ---------------- K1: embedding gather + xp0 = x @ w_ih_l0^T + b_ih + b_hh ------
// grid (4, 4088), block 256. xp[tb][g], tb = t*8+b.
__global__ void k_embed_xp0(const int* __restrict__ cap,
                            const float* __restrict__ emb,
                            const float* __restrict__ w_ih,
                            const float* __restrict__ b_ih,
                            const float* __restrict__ b_hh,
                            float* __restrict__ xp)
{
    const int g  = blockIdx.x * 256 + threadIdx.x;
    const int tb = blockIdx.y;
    const int t = tb >> 3, b = tb & 7;
    const int row = cap[b * 512 + t];                 // captions[:, :-1], t<511
    const float* xr = emb + (long)row * 128;
    const float* wr = w_ih + (long)g * 128;
    float acc = b_ih[g] + b_hh[g];
    #pragma unroll
    for (int k = 0; k < 128; k += 4) {
        float4 xv = *(const float4*)(xr + k);
        float4 wv = *(const float4*)(wr + k);
        acc += xv.x * wv.x + xv.y * wv.y + xv.z * wv.z + xv.w * wv.w;
    }
    xp[(long)tb * 1024 + g] = acc;
}

// ---------------- K3: xp1 = hs1 @ w_ih_l1^T + b_ih + b_hh ----------------------
__global__ void k_xp1(const unsigned short* __restrict__ hs1,
                      const float* __restrict__ w_ih,
                      const float* __restrict__ b_ih,
                      const float* __restrict__ b_hh,
                      float* __restrict__ xp)
{
    const int g  = blockIdx.x * 256 + threadIdx.x;
    const int tb = blockIdx.y;
    const unsigned short* xr = hs1 + (long)tb * 256;
    const float* wr = w_ih + (long)g * 256;
    float acc = b_ih[g] + b_hh[g];
    #pragma unroll 4
    for (int k = 0; k < 256; k += 4) {
        uint2 xv = *(const uint2*)(xr + k);           // 4 bf16
        float4 wv = *(const float4*)(wr + k);
        const unsigned short* xs = (const unsigned short*)&xv;
        acc += b2f(xs[0]) * wv.x + b2f(xs[1]) * wv.y + b2f(xs[2]) * wv.z + b2f(xs[3]) * wv.w;
    }
    xp[(long)tb * 1024 + g] = acc;
}

// ---------------- K2/K4: LSTM scan, one workgroup (16 waves), MFMA -------------
// gates(8x1024) = h(8x256) @ w_hh^T + xp[t]; M padded to 16 (rows 8..15 read a
// shared zero row). wave w owns n-tile columns j = w*16 + c for all 4 gates.
// A-frag: m=lane&15 (rows>=8 -> zero row), k=ki*32+(lane>>4)*8+j  (LDS hbuf, dbuf)
// B-frag: per (ki,gate) frag fi = ki*4+g, partitioned RESIDENT:
//           SRC 0 -> VGPR array breg[20]   (loaded once before the t-loop)
//           SRC 1 -> LDS wlds (9 frags/lane, 144 KB; each lane reads only its own)
//           SRC 2 -> streamed from L2 each step (3 frags, 48 KB/step, hidden)
// C: row(b)=(lane>>4)*4+reg, col=lane&15. xp[t] is folded into acc init.
__global__ __launch_bounds__(1024)
void k_scan(const float* __restrict__ xp,
            const unsigned short* __restrict__ w_hh,   // bf16, [1024][256]
            const float* __restrict__ h0,              // f32 [8][256]
            unsigned short* __restrict__ hs_out)       // bf16 [4088][256]
{
    // 9 rows: 0..7 real batch rows, row 8 = shared zero row for m=8..15
    __shared__ __align__(16) unsigned short hbuf[2][9][264];            // 9,504 B
    __shared__ __align__(16) unsigned short wlds[9 * 16 * 64 * 8];      // 147,456 B

    const int tid = threadIdx.x;
    const int w = tid >> 6, lane = tid & 63, q = lane >> 4, c = lane & 15;
    const int j = w * 16 + c;

    // frag source map, fi = ki*4+g:
    //   LDS (9):    g==2 for all ki, plus fi=15
    //   STREAM (3): fi in {11, 23, 31}
    //   REG (20):   the rest
    constexpr int SRC[32] = {0,0,1,0, 0,0,1,0, 0,0,1,2, 0,0,1,1,
                             0,0,1,0, 0,0,1,2, 0,0,1,0, 0,0,1,2};
    constexpr int IDX[32] = {0,1,0,2, 3,4,1,5, 6,7,2,0, 8,9,3,4,
                             10,11,5,12, 13,14,6,1, 15,16,7,17, 18,19,8,2};

    // per-lane base into w_hh: frag (ki,g) is at  wb + g*65536 + ki*32
    const unsigned short* wb = w_hh + (long)j * 256 + q * 8;

    // ---- load resident weights ----
    bf16x8 breg[20];
    #pragma unroll
    for (int fi = 0; fi < 32; ++fi) {
        const int ki = fi >> 2, g = fi & 3;
        if (SRC[fi] == 0)
            breg[IDX[fi]] = *(const bf16x8*)(wb + g * 65536 + ki * 32);
    }
    #pragma unroll
    for (int fi = 0; fi < 32; ++fi) {
        const int ki = fi >> 2, g = fi & 3;
        if (SRC[fi] == 1) {
            bf16x8 v = *(const bf16x8*)(wb + g * 65536 + ki * 32);
            *(bf16x8*)(wlds + ((IDX[fi] * 16 + w) * 64 + lane) * 8) = v;
        }
    }

    // ---- init hbuf: buf0 rows 0..7 = bf16(h0); row 8 of BOTH buffers = 0 ----
    for (int i = tid; i < 2 * 9 * 264; i += 1024) {
        const int bi = i / (9 * 264);
        const int rem = i % (9 * 264);
        const int r = rem / 264, k = rem % 264;
        unsigned short v = 0;
        if (bi == 0 && r < 8 && k < 256) v = f2b(h0[r * 256 + k]);
        ((unsigned short*)hbuf)[i] = v;
    }
    float cst[4] = {0.f, 0.f, 0.f, 0.f};
    __syncthreads();

    const unsigned short* hrow = &hbuf[0][(c < 8 ? c : 8)][q * 8];

    #pragma unroll 1
    for (int t = 0; t < 511; ++t) {
        const int rd = t & 1, wr_ = rd ^ 1;
        const unsigned short* hb = hrow + rd * (9 * 264);

        // acc init = xp[t] (rows 0..7), 0 for pad rows; loads issue before MFMAs
        f32x4 a[4];
        #pragma unroll
        for (int g = 0; g < 4; ++g) a[g] = (f32x4){0.f, 0.f, 0.f, 0.f};
        if (q < 2) {
            const float* xr = xp + (long)t * 8192 + j;
            #pragma unroll
            for (int r = 0; r < 4; ++r) {
                const int b = q * 4 + r;
                #pragma unroll
                for (int g = 0; g < 4; ++g) a[g][r] = xr[b * 1024 + g * 256];
            }
        }

        #pragma unroll
        for (int ki = 0; ki < 8; ++ki) {
            const bf16x8 af = *(const bf16x8*)(hb + ki * 32);
            #pragma unroll
            for (int g = 0; g < 4; ++g) {
                const int fi = ki * 4 + g;
                bf16x8 bf;
                if (SRC[fi] == 0)       bf = breg[IDX[fi]];
                else if (SRC[fi] == 1)  bf = *(const bf16x8*)(wlds + ((IDX[fi] * 16 + w) * 64 + lane) * 8);
                else                    bf = *(const bf16x8*)(wb + g * 65536 + ki * 32);
                a[g] = __builtin_amdgcn_mfma_f32_16x16x32_bf16(af, bf, a[g], 0, 0, 0);
            }
        }

        if (q < 2) {
            #pragma unroll
            for (int r = 0; r < 4; ++r) {
                const int b = q * 4 + r;
                float xi = a[0][r];
                float xf = a[1][r];
                float xg = a[2][r];
                float xo = a[3][r];
                float cn = sigmoidf_(xf) * cst[r] + sigmoidf_(xi) * tanhf_(xg);
                cst[r] = cn;
                float h = sigmoidf_(xo) * tanhf_(cn);
                unsigned short hv = f2b(h);
                hbuf[wr_][b][j] = hv;
                hs_out[((long)t * 8 + b) * 256 + j] = hv;
            }
        }
        __syncthreads();
    }
}

// ---------------- K5: gate scalar per (t,b) ------------------------------------
__global__ void k_gate(const unsigned short* __restrict__ hs2,   // bf16
                       const float* __restrict__ gw1,
                       const float* __restrict__ gb1,
                       const float* __restrict__ gw2,
                       const float* __restrict__ gb2,
                       float* __restrict__ gate)
{
    __shared__ float xr[256];
    __shared__ float wsum[4];
    const int tb = blockIdx.x, j = threadIdx.x;
    xr[j] = b2f(hs2[(long)tb * 256 + j]);
    __syncthreads();
    const float* wr = gw1 + (long)j * 256;
    float acc = gb1[j];
    #pragma unroll 4
    for (int k = 0; k < 256; k += 4) {
        float4 wv = *(const float4*)(wr + k);
        acc += xr[k] * wv.x + xr[k+1] * wv.y + xr[k+2] * wv.z + xr[k+3] * wv.w;
    }
    float uu = tanhf_(acc) * gw2[j];
    #pragma unroll
    for (int off = 32; off; off >>= 1) uu += __shfl_down(uu, off, 64);
    if ((j & 63) == 0) wsum[j >> 6] = uu;
    __syncthreads();
    if (j == 0) gate[tb] = sigmoidf_(wsum[0] + wsum[1] + wsum[2] + wsum[3] + gb2[0]);
}

// ---------------- K6: out = gate[m] * (hs2 @ out_w^T) + out_b ------------------
// 128x128 tile per block, 4 waves (2x2), frags direct from global (K-contiguous).
// grid (250, 32); m = t*8+b -> out[(b*511+t)*32000 + n]. Output f32.
__global__ __launch_bounds__(256)
void k_out(const unsigned short* __restrict__ hs2,    // bf16 [4096][256] (rows>=4088 unused)
           const float* __restrict__ gate,
           const unsigned short* __restrict__ out_w,  // bf16 [32000][256]
           const float* __restrict__ out_b,
           float* __restrict__ out)
{
    const int tid = threadIdx.x;
    const int wv = tid >> 6, lane = tid & 63, q = lane >> 4, c = lane & 15;
    const int wy = wv >> 1, wx = wv & 1;
    const int m0 = blockIdx.y * 128, n0 = blockIdx.x * 128;
    f32x4 acc[4][4];
    #pragma unroll
    for (int mt = 0; mt < 4; ++mt)
        #pragma unroll
        for (int nt = 0; nt < 4; ++nt) acc[mt][nt] = (f32x4){0.f, 0.f, 0.f, 0.f};

    #pragma unroll
    for (int ki = 0; ki < 8; ++ki) {
        bf16x8 af[4], bfr[4];
        #pragma unroll
        for (int mt = 0; mt < 4; ++mt) {
            const int m = min(m0 + wy * 64 + mt * 16 + c, 4087);   // clamp: never read pad
            af[mt] = *(const bf16x8*)(hs2 + (long)m * 256 + ki * 32 + q * 8);
        }
        #pragma unroll
        for (int nt = 0; nt < 4; ++nt) {
            const int n = n0 + wx * 64 + nt * 16 + c;
            bfr[nt] = *(const bf16x8*)(out_w + (long)n * 256 + ki * 32 + q * 8);
        }
        #pragma unroll
        for (int mt = 0; mt < 4; ++mt)
            #pragma unroll
            for (int nt = 0; nt < 4; ++nt)
                acc[mt][nt] = __builtin_amdgcn_mfma_f32_16x16x32_bf16(af[mt], bfr[nt], acc[mt][nt], 0, 0, 0);
    }

    #pragma unroll
    for (int mt = 0; mt < 4; ++mt) {
        #pragma unroll
        for (int r = 0; r < 4; ++r) {
            const int m = m0 + wy * 64 + mt * 16 + q * 4 + r;
            if (m < 4088) {
                const int t = m >> 3, b = m & 7;
                const float gm = gate[m];
                const long obase = ((long)b * 511 + t) * 32000 + n0 + wx * 64;
                #pragma unroll
                for (int nt = 0; nt < 4; ++nt) {
                    const int n = n0 + wx * 64 + nt * 16 + c;
                    out[obase + nt * 16 + c] = gm * acc[mt][nt][r] + out_b[n];
                }
            }
        }
    }
}

extern "C" void kernel_launch(void* const* d_in, const int* in_sizes, int n_in,
                              void* d_out, int out_size, void* d_ws, size_t ws_size,
                              hipStream_t stream)
{
    const float* thought = (const float*)d_in[0];
    const int*   cap     = (const int*)d_in[1];
    const float* emb     = (const float*)d_in[2];
    const float* w_ih0   = (const float*)d_in[3];
    const float* w_hh0   = (const float*)d_in[4];
    const float* b_ih0   = (const float*)d_in[5];
    const float* b_hh0   = (const float*)d_in[6];
    const float* w_ih1   = (const float*)d_in[7];
    const float* w_hh1   = (const float*)d_in[8];
    const float* b_ih1   = (const float*)d_in[9];
    const float* b_hh1   = (const float*)d_in[10];
    const float* gw1     = (const float*)d_in[11];
    const float* gb1     = (const float*)d_in[12];
    const float* gw2     = (const float*)d_in[13];
    const float* gb2     = (const float*)d_in[14];
    const float* ow      = (const float*)d_in[15];
    const float* ob      = (const float*)d_in[16];

    char* ws = (char*)d_ws;
    float*          xp    = (float*)(ws);
    unsigned short* hs1   = (unsigned short*)(ws + 16744448);
    unsigned short* hs2   = (unsigned short*)(ws + 18841600);
    float*          gate  = (float*)(ws + 20938752);
    unsigned short* whh0b = (unsigned short*)(ws + 20955104);
    unsigned short* whh1b = (unsigned short*)(ws + 21479392);
    unsigned short* owb   = (unsigned short*)(ws + 22003680);
    float*          out   = (float*)d_out;

    k_cvt<<<dim3(256),  256, 0, stream>>>(w_hh0, whh0b, 262144);
    k_cvt<<<dim3(256),  256, 0, stream>>>(w_hh1, whh1b, 262144);
    k_cvt<<<dim3(8000), 256, 0, stream>>>(ow, owb, 8192000);

    k_embed_xp0<<<dim3(4, 4088), 256, 0, stream>>>(cap, emb, w_ih0, b_ih0, b_hh0, xp);
    k_scan<<<1, 1024, 0, stream>>>(xp, whh0b, thought, hs1);
    k_xp1<<<dim3(4, 4088), 256, 0, stream>>>(hs1, w_ih1, b_ih1, b_hh1, xp);
    k_scan<<<1, 1024, 0, stream>>>(xp, whh1b, thought, hs2);
    k_gate<<<4088, 256, 0, stream>>>(hs2, gw1, gb1, gw2, gb2, gate);
    k_out<<<dim3(250, 32), 256, 0, stream>>>(hs2, gate, owb, ob, out);
}